// Round 4
// baseline (1644.899 us; speedup 1.0000x reference)
//
#include <hip/hip_runtime.h>
#include <cstdint>
#include <cstddef>

#define N_TOK 65536
#define DIM 512
#define FF 2048
#define NE 8

typedef __attribute__((ext_vector_type(8))) short short8;
typedef __attribute__((ext_vector_type(16))) float f32x16;

__device__ __forceinline__ unsigned f2bf(float f) {
  unsigned u = __builtin_bit_cast(unsigned, f);
  u = u + 0x7fffu + ((u >> 16) & 1u);
  return (u >> 16) & 0xffffu;
}

__device__ __forceinline__ void gload_lds16(const void* g, void* l) {
  __builtin_amdgcn_global_load_lds((const __attribute__((address_space(1))) void*)g,
                                   (__attribute__((address_space(3))) void*)l, 16, 0, 0);
}

#define SBAR __builtin_amdgcn_sched_barrier(0)
#define BARN(N) do { SBAR; \
  asm volatile("s_waitcnt vmcnt(" #N ")" ::: "memory"); \
  __builtin_amdgcn_s_barrier(); SBAR; } while (0)
#define BARNL(N) do { SBAR; \
  asm volatile("s_waitcnt vmcnt(" #N ") lgkmcnt(0)" ::: "memory"); \
  __builtin_amdgcn_s_barrier(); SBAR; } while (0)

// ---------------- transpose + cast: in (rows x cols) f32 -> out (cols x rows) bf16, per expert
__global__ __launch_bounds__(256) void k_transpose_cast(
    const float* __restrict__ in, unsigned short* __restrict__ outp, int rows, int cols)
{
  __shared__ float tile[32][33];
  const float* ine = in + (size_t)blockIdx.z * rows * cols;
  unsigned short* oute = outp + (size_t)blockIdx.z * rows * cols;
  int tx = threadIdx.x & 31, ty = threadIdx.x >> 5;
  int r0 = blockIdx.y * 32, c0 = blockIdx.x * 32;
#pragma unroll
  for (int i = 0; i < 4; ++i)
    tile[ty + i*8][tx] = ine[(size_t)(r0 + ty + i*8)*cols + c0 + tx];
  __syncthreads();
#pragma unroll
  for (int i = 0; i < 4; ++i) {
    int r = c0 + ty + i*8, c = r0 + tx;
    oute[(size_t)r*rows + c] = (unsigned short)f2bf(tile[tx][ty + i*8]);
  }
}

// ---------------- router pass 1: logits, top-2, weight; per-expert counts only
__global__ __launch_bounds__(256) void k_router(
    const float* __restrict__ x, const float* __restrict__ Wr,
    int2* __restrict__ tinfo, int* __restrict__ cnt)
{
  __shared__ int lcnt[8];
  int tid = threadIdx.x, lane = tid & 63, wv = tid >> 6;
  if (tid < 8) lcnt[tid] = 0;
  float wr[8][8];
#pragma unroll
  for (int j = 0; j < 8; ++j) {
    const float4* p = (const float4*)(Wr + (size_t)(lane*8 + j)*NE);
    float4 a = p[0], b = p[1];
    wr[j][0]=a.x; wr[j][1]=a.y; wr[j][2]=a.z; wr[j][3]=a.w;
    wr[j][4]=b.x; wr[j][5]=b.y; wr[j][6]=b.z; wr[j][7]=b.w;
  }
  __syncthreads();
  int t0 = blockIdx.x*64 + wv*16;
  for (int it = 0; it < 16; ++it) {
    int t = t0 + it;
    const float4* xp = (const float4*)(x + (size_t)t*DIM + lane*8);
    float4 v0 = xp[0], v1 = xp[1];
    float xv[8] = {v0.x,v0.y,v0.z,v0.w,v1.x,v1.y,v1.z,v1.w};
    float lg[8];
#pragma unroll
    for (int e2 = 0; e2 < 8; ++e2) lg[e2] = 0.f;
#pragma unroll
    for (int j = 0; j < 8; ++j)
#pragma unroll
      for (int e2 = 0; e2 < 8; ++e2) lg[e2] += xv[j]*wr[j][e2];
#pragma unroll
    for (int off = 32; off >= 1; off >>= 1)
#pragma unroll
      for (int e2 = 0; e2 < 8; ++e2) lg[e2] += __shfl_xor(lg[e2], off, 64);
    int e0 = 0; float v0m = lg[0];
#pragma unroll
    for (int e2 = 1; e2 < 8; ++e2) if (lg[e2] > v0m) { v0m = lg[e2]; e0 = e2; }
    int e1 = -1; float v1m = -3.0e38f;
#pragma unroll
    for (int e2 = 0; e2 < 8; ++e2) if (e2 != e0 && lg[e2] > v1m) { v1m = lg[e2]; e1 = e2; }
    float w0 = 1.f / (1.f + __expf((v1m - v0m) * 0.4f));   // 1/T = 1/2.5
    if (lane == 0) {
      atomicAdd(&lcnt[e0], 1);
      atomicAdd(&lcnt[e1], 1);
      tinfo[t] = make_int2(e0 | (e1 << 8), __float_as_int(w0));
    }
  }
  __syncthreads();
  if (tid < 8) atomicAdd(&cnt[tid*16], lcnt[tid]);
}

// ---------------- pass 2: exclusive scan of counts -> bases; zero cursors
__global__ void k_offsets(int* cnt) {
  if (threadIdx.x == 0) {
    int base = 0;
    for (int e2 = 0; e2 < 8; ++e2) {
      cnt[e2*16 + 1] = base;
      base += cnt[e2*16];
      cnt[e2*16 + 2] = 0;
    }
  }
}

// ---------------- pass 3: gather x rows (bf16) into contiguous per-expert regions
__global__ __launch_bounds__(256) void k_fill(
    const float* __restrict__ x, const int2* __restrict__ tinfo,
    unsigned short* __restrict__ xg, int* __restrict__ tokl,
    float* __restrict__ pwl, int* __restrict__ cnt)
{
  __shared__ int lc[8], lbase[8], gb[8];
  __shared__ unsigned char ce[128];
  __shared__ int csl[128];
  __shared__ float cw[128];
  int tid = threadIdx.x;
  if (tid < 8) { lc[tid] = 0; gb[tid] = cnt[tid*16 + 1]; }
  __syncthreads();
  if (tid < 64) {
    int t = blockIdx.x*64 + tid;
    int2 inf = tinfo[t];
    int e0 = inf.x & 0xff, e1 = (inf.x >> 8) & 0xff;
    float w0 = __int_as_float(inf.y);
    int i0 = tid*2, i1 = i0 + 1;
    ce[i0] = (unsigned char)e0; cw[i0] = w0;        csl[i0] = atomicAdd(&lc[e0], 1);
    ce[i1] = (unsigned char)e1; cw[i1] = 1.f - w0;  csl[i1] = atomicAdd(&lc[e1], 1);
  }
  __syncthreads();
  if (tid < 8) lbase[tid] = atomicAdd(&cnt[tid*16 + 2], lc[tid]);
  __syncthreads();
  int lane = tid & 63, wv = tid >> 6;
#pragma unroll
  for (int j = 0; j < 32; ++j) {
    int i = wv*32 + j;
    int t = blockIdx.x*64 + (i >> 1);
    int e2 = ce[i];
    int gpos = gb[e2] + lbase[e2] + csl[i];
    const float4* src = (const float4*)(x + (size_t)t*DIM + lane*8);
    float4 v0 = src[0], v1 = src[1];
    uint4 pk;
    pk.x = f2bf(v0.x) | (f2bf(v0.y) << 16);
    pk.y = f2bf(v0.z) | (f2bf(v0.w) << 16);
    pk.z = f2bf(v1.x) | (f2bf(v1.y) << 16);
    pk.w = f2bf(v1.z) | (f2bf(v1.w) << 16);
    *(uint4*)(xg + (size_t)gpos*DIM + lane*8) = pk;
    if (lane == 0) { tokl[gpos] = t; pwl[gpos] = cw[i]; }
  }
}

// ---------------- fused expert FFN v4: 128 rows/block, 8 waves, 32x32x16 MFMA
// A (x) staged via LDS from contiguous xg (coalesced gload_lds, source-pre-swizzled).
// G1: wave = 32tok x 64f (grid 4x2). K32 phases, xs 2-buf dist-1, w1 4-buf dist-2.
// G2: wave = 64tok x 128d (grid 2x4). K32 phases (w2 chunks 512d x 32k), 2-buf.
// Swizzles: xs/w1/w2 slot ^= ((row>>1)&3) -> 4-way max; hsm rows 132 shorts -> 2-way free.
__global__ __launch_bounds__(512, 2) void k_ffn(
    const unsigned short* __restrict__ xg,
    const unsigned short* __restrict__ w1t,   // (E, F, D) bf16
    const unsigned short* __restrict__ w2t,   // (E, D, F) bf16
    const float* __restrict__ b1, const float* __restrict__ b2,
    const int* __restrict__ tokl, const float* __restrict__ pwl,
    const int* __restrict__ cnt, float* __restrict__ out)
{
  const int e = blockIdx.x & 7;            // expert <-> XCD affinity
  const int tile = blockIdx.x >> 3;
  const int count = cnt[e*16];
  const int gbase = cnt[e*16 + 1];
  const int row0 = tile * 128;
  if (row0 >= count) return;

  __shared__ __align__(16) unsigned short xs[2][4096];    // 8KB: [128t][32k]
  __shared__ __align__(16) unsigned short w1s[4][4096];   // 8KB: [128f][32k]
  __shared__ __align__(16) unsigned short w2s[2][16384];  // 32KB: [512d][32k]
  __shared__ __align__(16) unsigned short hsm[128*132];   // 33KB, 264B rows (2-way free)
  __shared__ __align__(16) float b1s[FF];                 // 8KB

  const int tid = threadIdx.x, lane = tid & 63, wv = tid >> 6;
  const int l31 = lane & 31, hi = lane >> 5;
  const int tg = wv >> 1, fg = wv & 1;      // G1 wave coords
  const int rg2 = wv >> 2, cg2 = wv & 3;    // G2 wave coords
  const int tr = (l31 >> 1) & 3;            // read-side slot XOR (same for xs/w1/w2)

  const unsigned short* w1e = w1t + (size_t)e*FF*DIM;
  const unsigned short* w2e = w2t + (size_t)e*DIM*FF;
  const unsigned short* xge = xg + (size_t)(gbase + row0)*DIM;

  const int srow = tid >> 2, sslot = tid & 3;          // staging thread coords
  const int sxor = (srow >> 1) & 3;

  auto stage_xs = [&](int buf, int kc) {
    const unsigned short* src = xge + (size_t)srow*DIM + kc*32 + ((sslot ^ sxor)*8);
    gload_lds16(src, &xs[buf][wv*512]);
  };
  auto stage_w1 = [&](int buf, int f0_, int k0_) {
    const unsigned short* src = w1e + (size_t)(f0_ + srow)*DIM + k0_ + ((sslot ^ sxor)*8);
    gload_lds16(src, &w1s[buf][wv*512]);
  };
  auto stage_w2 = [&](int buf, int k0_) {              // k0_ = f-offset of 32-wide chunk
#pragma unroll
    for (int j = 0; j < 4; ++j) {
      int d = j*128 + srow;
      const unsigned short* src = w2e + (size_t)d*FF + k0_ + ((sslot ^ (((d >> 1) & 3)))*8);
      gload_lds16(src, &w2s[buf][j*4096 + wv*512]);
    }
  };

  const f32x16 fz = {0,0,0,0,0,0,0,0,0,0,0,0,0,0,0,0};
  f32x16 acc[2][4];
#pragma unroll
  for (int m = 0; m < 2; ++m)
#pragma unroll
    for (int n = 0; n < 4; ++n) acc[m][n] = fz;

  // ---- prologue: b1 -> LDS (+1), xs chunk0 (+1), w1 chunk0/1 (+2) ----
  gload_lds16(b1 + (size_t)e*FF + tid*4, &b1s[wv*256]); SBAR;
  stage_xs(0, 0); SBAR;
  stage_w1(0, 0, 0); SBAR;
  stage_w1(1, 0, 32); SBAR;

  for (int fi = 0; fi < 16; ++fi) {
    const int f0 = fi << 7;
    const int f0n = f0 + 128;                // next fi (OOB-harmless at fi=15)
    f32x16 hacc[2] = {fz, fz};

    // ---------- GEMM1: 16 K32-phases ----------
#pragma unroll
    for (int kk = 0; kk < 16; ++kk) {
      if (kk == 15) { BARN(5); } else { BARN(1); }
      if (kk < 14) {
        stage_xs((kk + 1) & 1, kk + 1); SBAR;
        stage_w1((kk + 2) & 3, f0, (kk + 2)*32); SBAR;
      } else if (kk == 14) {
        stage_xs(1, 15); SBAR;
        stage_w1(0, f0n, 0); SBAR;           // next-fi chunk 0
        stage_w2(0, f0); SBAR;               // G2 chunk 0 (dist-2)
      } else {
        stage_xs(0, 0); SBAR;                // next-fi k=0 (cyclic)
        stage_w1(1, f0n, 32); SBAR;          // next-fi chunk 1
      }
      __builtin_amdgcn_s_setprio(1);
#pragma unroll
      for (int s = 0; s < 2; ++s) {
        short8 a = *(const short8*)&xs[kk & 1][(tg*32 + l31)*32 + (((s*2 + hi) ^ tr)*8)];
#pragma unroll
        for (int n = 0; n < 2; ++n) {
          int f = fg*64 + n*32 + l31;
          short8 b = *(const short8*)&w1s[kk & 3][f*32 + (((s*2 + hi) ^ tr)*8)];
          hacc[n] = __builtin_amdgcn_mfma_f32_32x32x16_bf16(a, b, hacc[n], 0, 0, 0);
        }
      }
      __builtin_amdgcn_s_setprio(0);
    }

    // ---------- bias + gelu -> hsm (2-way-free padded rows) ----------
#pragma unroll
    for (int n = 0; n < 2; ++n) {
      int f = fg*64 + n*32 + l31;
      float bias = b1s[f0 + f];
#pragma unroll
      for (int r = 0; r < 16; ++r) {
        int row = tg*32 + (r & 3) + 8*(r >> 2) + 4*hi;
        float v = hacc[n][r] + bias;
        float u = 0.7978845608028654f * (v + 0.044715f*v*v*v);
        float g = v / (1.f + __expf(-2.f*u));          // tanh-approx gelu
        hsm[row*132 + f] = (unsigned short)f2bf(g);
      }
    }

    // ---------- GEMM2: 4 K32-phases ----------
#pragma unroll
    for (int c = 0; c < 4; ++c) {
      if (c == 0) { BARNL(2); } else { BARN(0); }
      if (c < 3) { stage_w2((c + 1) & 1, f0 + (c + 1)*32); SBAR; }
      __builtin_amdgcn_s_setprio(1);
#pragma unroll
      for (int s2 = 0; s2 < 2; ++s2) {
        short8 a0 = *(const short8*)&hsm[(rg2*64 + l31)*132 + c*32 + s2*16 + hi*8];
        short8 a1 = *(const short8*)&hsm[(rg2*64 + 32 + l31)*132 + c*32 + s2*16 + hi*8];
#pragma unroll
        for (int n = 0; n < 4; ++n) {
          int d = cg2*128 + n*32 + l31;
          short8 b = *(const short8*)&w2s[c & 1][d*32 + (((s2*2 + hi) ^ tr)*8)];
          acc[0][n] = __builtin_amdgcn_mfma_f32_32x32x16_bf16(a0, b, acc[0][n], 0, 0, 0);
          acc[1][n] = __builtin_amdgcn_mfma_f32_32x32x16_bf16(a1, b, acc[1][n], 0, 0, 0);
        }
      }
      __builtin_amdgcn_s_setprio(0);
    }
  }

  // ---------- epilogue: weighted atomic scatter-add ----------
  float b2v[4];
#pragma unroll
  for (int n = 0; n < 4; ++n) b2v[n] = b2[e*DIM + cg2*128 + n*32 + l31];
#pragma unroll
  for (int m = 0; m < 2; ++m) {
#pragma unroll
    for (int r = 0; r < 16; ++r) {
      int grow = row0 + rg2*64 + m*32 + (r & 3) + 8*(r >> 2) + 4*hi;
      if (grow < count) {
        int tk = tokl[gbase + grow];
        float wg = pwl[gbase + grow];
#pragma unroll
        for (int n = 0; n < 4; ++n) {
          int d = cg2*128 + n*32 + l31;
          atomicAdd(out + (size_t)tk*DIM + d, (acc[m][n][r] + b2v[n]) * wg);
        }
      }
    }
  }
}

extern "C" void kernel_launch(void* const* d_in, const int* in_sizes, int n_in,
                              void* d_out, int out_size, void* d_ws, size_t ws_size,
                              hipStream_t stream)
{
  const float* x  = (const float*)d_in[0];
  const float* Wr = (const float*)d_in[1];
  const float* W1 = (const float*)d_in[2];
  const float* b1 = (const float*)d_in[3];
  const float* W2 = (const float*)d_in[4];
  const float* b2 = (const float*)d_in[5];
  float* out = (float*)d_out;
  (void)in_sizes; (void)n_in; (void)ws_size;

  char* ws = (char*)d_ws;
  unsigned short* xg  = (unsigned short*)(ws);                    // 128 MB gathered activations
  unsigned short* w1t = (unsigned short*)(ws + 134217728);        // 16 MB W1^T bf16
  unsigned short* w2t = (unsigned short*)(ws + 150994944);        // 16 MB W2^T bf16
  int2*  tinfo = (int2*)(ws + 167772160);                         // 512 KB per-token routing
  int*   tokl  = (int*)(ws + 168296448);                          // 512 KB token list (global pos)
  float* pwl   = (float*)(ws + 168820736);                        // 512 KB pair weights
  int*   cnt   = (int*)(ws + 169345024);                          // 512 B counts/bases/cursors

  hipMemsetAsync(cnt, 0, NE*16*sizeof(int), stream);
  hipMemsetAsync(d_out, 0, (size_t)out_size*sizeof(float), stream);

  dim3 g1(FF/32, DIM/32, NE);
  k_transpose_cast<<<g1, 256, 0, stream>>>(W1, w1t, DIM, FF);
  dim3 g2(DIM/32, FF/32, NE);
  k_transpose_cast<<<g2, 256, 0, stream>>>(W2, w2t, FF, DIM);

  k_router<<<N_TOK/64, 256, 0, stream>>>(x, Wr, tinfo, cnt);
  k_offsets<<<1, 64, 0, stream>>>(cnt);
  k_fill<<<N_TOK/64, 256, 0, stream>>>(x, tinfo, xg, tokl, pwl, cnt);

  k_ffn<<<NE * (N_TOK/128), 512, 0, stream>>>(xg, w1t, w2t, b1, b2, tokl, pwl, cnt, out);
}